// Round 6
// baseline (12100.094 us; speedup 1.0000x reference)
//
#include <hip/hip_runtime.h>
#include <stdint.h>
#include <math.h>

#define HH   512
#define BB   64
#define TT   2000
#define NEXC 409          // int(0.8 * 512)
#define SLICE  128        // hidden units owned per block
#define NBLK   (BB * 4)   // 256 blocks = 1 per CU

// Python-float constants, rounded to f32 exactly as the reference does.
constexpr float ALPHA_F     = 0.1f;
constexpr float IN_SCALE_F  = (float)4.4721359549995794e-03;
constexpr float REC_SCALE_F = (float)4.4721359549995794e-02;
constexpr float SQRT2_F     = 1.41421356237309515f;
constexpr float U_LO        = -0x1.fffffep-1f;

struct U2 { uint32_t a, b; };

__host__ __device__ constexpr uint32_t rotl32(uint32_t x, int d) {
  return (x << d) | (x >> (32 - d));
}

// JAX Threefry-2x32, 20 rounds.
__host__ __device__ constexpr U2 tf2x32(uint32_t k0, uint32_t k1,
                                        uint32_t x0, uint32_t x1) {
  uint32_t ks[3] = {k0, k1, k0 ^ k1 ^ 0x1BD11BDAu};
  const int R[2][4] = {{13, 15, 26, 6}, {17, 29, 16, 24}};
  x0 += ks[0]; x1 += ks[1];
  for (int g = 0; g < 5; ++g) {
    const int* r = R[g & 1];
    for (int i = 0; i < 4; ++i) { x0 += x1; x1 = rotl32(x1, r[i]); x1 ^= x0; }
    x0 += ks[(g + 1) % 3];
    x1 += ks[(g + 2) % 3] + (uint32_t)(g + 1);
  }
  return U2{x0, x1};
}

constexpr U2 KIN_  = tf2x32(0u, 42u, 0u, 0u);
constexpr U2 KREC_ = tf2x32(0u, 42u, 0u, 1u);
constexpr uint32_t KIN0 = KIN_.a,  KIN1 = KIN_.b;
constexpr uint32_t KRC0 = KREC_.a, KRC1 = KREC_.b;

__device__ __forceinline__ float jax_normal(uint32_t k0, uint32_t k1, uint32_t idx) {
  U2 o = tf2x32(k0, k1, 0u, idx);
  uint32_t bits = o.a ^ o.b;
  float f = __uint_as_float((bits >> 9) | 0x3f800000u) - 1.0f;  // [0,1)
  float u = fmaxf(U_LO, f * 2.0f + U_LO);
  float w = -log1pf(-u * u);
  float p;
  if (w < 5.0f) {
    w = w - 2.5f;
    p =             2.81022636e-08f;
    p = fmaf(p, w,  3.43273939e-07f);
    p = fmaf(p, w, -3.5233877e-06f);
    p = fmaf(p, w, -4.39150654e-06f);
    p = fmaf(p, w,  0.00021858087f);
    p = fmaf(p, w, -0.00125372503f);
    p = fmaf(p, w, -0.00417768164f);
    p = fmaf(p, w,  0.246640727f);
    p = fmaf(p, w,  1.50140941f);
  } else {
    w = sqrtf(w) - 3.0f;
    p =            -0.000200214257f;
    p = fmaf(p, w,  0.000100950558f);
    p = fmaf(p, w,  0.00134934322f);
    p = fmaf(p, w, -0.00367342844f);
    p = fmaf(p, w,  0.00573950773f);
    p = fmaf(p, w, -0.0076224613f);
    p = fmaf(p, w,  0.00943887047f);
    p = fmaf(p, w,  1.00167406f);
    p = fmaf(p, w,  2.83297682f);
  }
  return SQRT2_F * (p * u);
}

// Workspace: two tagged-word buffers, each pub[2][BB][HH] uint64 = 512 KB:
//   fast @ offset 0      — exchanged through the XCD-local L2 (sc0 ops);
//   safe @ offset 512 KB — agent-scope (MALL) backup, read only on fallback.
// word = (step_tag << 32) | f32bits(relu(h)); slot parity = tag & 1.
#define PUB_BYTES   (2 * BB * HH * 8)           // 512 KB per buffer
#define SAFE_OFF_W  (2 * BB * HH)               // uint64 offset of safe buffer

// XCD-local L2 transport: sc0 = bypass L1, stop at L2 (NOT sc1 -> not MALL).
__device__ __forceinline__ void st_l2(uint64_t* p, uint64_t v) {
  asm volatile("global_store_dwordx2 %0, %1, off sc0"
               :: "v"(p), "v"(v) : "memory");
}
__device__ __forceinline__ uint64_t ld_l2(const uint64_t* p) {
  uint64_t r;
  asm volatile("global_load_dwordx2 %0, %1, off sc0\n\t"
               "s_waitcnt vmcnt(0)"
               : "=v"(r) : "v"(p) : "memory");
  return r;
}

__global__ __launch_bounds__(512, 2)
void zrnn_main(const float* __restrict__ i_stim, const float* __restrict__ i_cc,
               const float* __restrict__ hidden0,
               const float* __restrict__ w_ih, const float* __restrict__ w_hh,
               const float* __restrict__ b_hh,
               const float* __restrict__ w_ho, const float* __restrict__ b_ho,
               float* __restrict__ outs, float* __restrict__ hids,
               uint64_t* __restrict__ pub) {
  // blockIdx -> (batch b, slice s); bid%8 == b&7, so the 4 slice-siblings of a
  // batch share an XCD under round-robin dispatch. This is a PERF assumption
  // for the fast path; the safe (agent-scope) path keeps it correct if wrong.
  const int bid  = blockIdx.x;
  const int low3 = bid & 7;
  const int q    = bid >> 3;
  const int s    = q & 3;
  const int b    = ((q >> 2) << 3) + low3;
  const int tid  = threadIdx.x;
  const int lane = tid & 63;
  const int wv   = tid >> 6;          // wave id = i-chunk id

  __shared__ float stim_s[TT];
  __shared__ float cc_s[TT];
  __shared__ float red[8][SLICE];     // per-wave matvec partials
  __shared__ float rloc[SLICE];       // own-slice relu(h) fast path (LDS)
  __shared__ float nbuf[4][SLICE];    // n_rec, 4 steps ahead
  __shared__ float nin_s[4][2];       // n_in,  4 steps ahead
  __shared__ float obuf[8];           // block-0 output partials

  // Preload this batch's input streams (16 KB LDS), coalesced.
  for (int idx = tid; idx < TT; idx += 512) {
    stim_s[idx] = i_stim[b * TT + idx];
    cc_s[idx]   = i_cc[b * TT + idx];
  }

  // Weight slice in REGISTERS: thread (wv,lane) holds wt[i][j] for
  // i in [64*wv, 64*wv+64), j in {jA, jB}.  wt[i][j] = |w_hh[j][i]|*(i!=j)*ei[i].
  const int jA = s * SLICE + lane;
  const int jB = jA + 64;
  const int i0 = wv * 64;
  float wA[64], wB[64];
  #pragma unroll
  for (int k4 = 0; k4 < 16; ++k4) {
    float4 a4 = *reinterpret_cast<const float4*>(&w_hh[jA * HH + i0 + k4 * 4]);
    float4 b4 = *reinterpret_cast<const float4*>(&w_hh[jB * HH + i0 + k4 * 4]);
    const float av[4] = {a4.x, a4.y, a4.z, a4.w};
    const float bv[4] = {b4.x, b4.y, b4.z, b4.w};
    #pragma unroll
    for (int c = 0; c < 4; ++c) {
      const int i = i0 + k4 * 4 + c;
      float va = (i == jA) ? 0.0f : fabsf(av[c]);
      float vb = (i == jB) ? 0.0f : fabsf(bv[c]);
      wA[k4 * 4 + c] = (i < NEXC) ? va : -va;
      wB[k4 * 4 + c] = (i < NEXC) ? vb : -vb;
    }
  }

  // Hidden-state owners: threads 0..127 own j = s*128 + tid.
  float h = 0.0f, wih0 = 0.0f, wih1 = 0.0f, bhh = 0.0f;
  const int jown = s * SLICE + tid;
  if (tid < SLICE) {
    h    = hidden0[b * HH + jown];
    wih0 = w_ih[jown * 2 + 0];
    wih1 = w_ih[jown * 2 + 1];
    bhh  = b_hh[jown];
  }
  // Block s==0 computes the output scalar from its full rv vector.
  float who_f = 0.0f, bho = 0.0f;
  if (s == 0) { who_f = w_ho[tid]; bho = b_ho[0]; }

  // rv: lane mapping i = tid; primed from hidden0.
  float rv = fmaxf(hidden0[b * HH + tid], 0.0f);

  // Noise prefill for steps 0..3.
  {
    const int tp = tid >> 7;
    const int jn = tid & 127;
    nbuf[tp][jn] = jax_normal(KRC0, KRC1,
        (uint32_t)tp * (uint32_t)(BB * HH) + (uint32_t)(b * HH + s * SLICE + jn));
    if (tid < 8) {
      const int tp2  = tid >> 1;
      const int slot = tid & 1;
      nin_s[tp2][slot] = jax_normal(KIN0, KIN1,
          (uint32_t)(tp2 * (BB * 2) + b * 2 + slot));
    }
  }

  const int  ownLo     = s * SLICE;
  const bool isOwnLane = (tid >= ownLo) && (tid < ownLo + SLICE);
  uint64_t* fast_b0 = pub + (size_t)b * HH;
  uint64_t* fast_b1 = pub + (size_t)(BB + b) * HH;
  uint64_t* safe_b0 = pub + SAFE_OFF_W + (size_t)b * HH;
  uint64_t* safe_b1 = pub + SAFE_OFF_W + (size_t)(BB + b) * HH;
  float* __restrict__ hid_out = hids + (size_t)b * TT * HH;

  __syncthreads();

  for (int t = 0; t < TT; ++t) {
    // Block 0: previous step's output scalar from rv (tag t) — off critical path.
    if (s == 0 && t > 0) {
      float v = rv * who_f;
      #pragma unroll
      for (int off = 32; off > 0; off >>= 1) v += __shfl_down(v, off);
      if (lane == 0) obuf[wv] = v;
    }

    // A: matvec partials — readlane-broadcast rv, register weights.
    float accA = 0.0f, accB = 0.0f;
    #pragma unroll
    for (int k = 0; k < 64; ++k) {
      float rk = __uint_as_float(__builtin_amdgcn_readlane(__float_as_uint(rv), k));
      accA = fmaf(rk, wA[k], accA);
      accB = fmaf(rk, wB[k], accB);
    }
    red[wv][lane]      = accA;
    red[wv][64 + lane] = accB;
    __syncthreads();  // barrier 1: red ready (also orders obuf write -> read)

    const int par = t & 1;
    uint64_t* fast_t = par ? fast_b1 : fast_b0;
    uint64_t* safe_t = par ? safe_b1 : safe_b0;

    // C: owners combine chunks (increasing-i), update h, publish tagged word.
    if (tid < SLICE) {
      float acc = red[0][tid];
      #pragma unroll
      for (int w = 1; w < 8; ++w) acc += red[w][tid];
      float nr = nbuf[t & 3][tid];
      float hid_hid = acc + bhh + REC_SCALE_F * nr;
      float ni0 = nin_s[t & 3][0];
      float ni1 = nin_s[t & 3][1];
      float cur0 = fmaxf(stim_s[t] + IN_SCALE_F * ni0, 0.0f);
      float cur1 = fmaxf(cc_s[t]   + IN_SCALE_F * ni1, 0.0f);
      float hid_in = cur0 * wih0 + cur1 * wih1;
      h = h + (-h + hid_in + hid_hid) * ALPHA_F;
      float r = fmaxf(h, 0.0f);
      uint64_t wd = ((uint64_t)(uint32_t)(t + 1) << 32) |
                    (uint64_t)__float_as_uint(r);
      st_l2(&fast_t[jown], wd);                 // XCD-L2 fast publish
      __hip_atomic_store(&safe_t[jown], wd, __ATOMIC_RELAXED,
                         __HIP_MEMORY_SCOPE_AGENT);  // MALL backup, no wait
      rloc[tid] = r;
      __builtin_nontemporal_store(h, hid_out + (size_t)t * HH + jown);
      if (s == 0 && tid == 0 && t > 0) {
        float p = ((obuf[0] + obuf[1]) + (obuf[2] + obuf[3])) +
                  ((obuf[4] + obuf[5]) + (obuf[6] + obuf[7]));
        outs[b * TT + (t - 1)] = p + bho;
      }
    }
    __syncthreads();  // barrier 2: rloc ready; red free for reuse

    // F: overlap the wait with noise precompute for t+1..t+4.
    if ((t & 3) == 3 && t + 1 < TT) {
      const int tp = t + 1 + (tid >> 7);
      if (tp < TT) {
        const int jn = tid & 127;
        nbuf[tp & 3][jn] = jax_normal(KRC0, KRC1,
            (uint32_t)tp * (uint32_t)(BB * HH) + (uint32_t)(b * HH + s * SLICE + jn));
      }
      if (tid < 8) {
        const int tp2  = t + 1 + (tid >> 1);
        const int slot = tid & 1;
        if (tp2 < TT)
          nin_s[tp2 & 3][slot] = jax_normal(KIN0, KIN1,
              (uint32_t)((tp2) * (BB * 2) + b * 2 + slot));
      }
    }

    // H: refresh rv. Own slice via LDS; remote via L2 tagged-word poll with
    // agent-scope fallback (correct even if the XCD mapping assumption fails).
    if (isOwnLane) {
      rv = rloc[tid - ownLo];
    } else {
      const uint32_t tagw = (uint32_t)(t + 1);
      uint64_t w = ld_l2(&fast_t[tid]);
      if ((uint32_t)(w >> 32) != tagw) {
        int spins = 0;
        for (;;) {
          w = ld_l2(&fast_t[tid]);
          if ((uint32_t)(w >> 32) == tagw) break;
          if (++spins > 32) {                    // fallback: MALL backup word
            w = __hip_atomic_load(&safe_t[tid], __ATOMIC_RELAXED,
                                  __HIP_MEMORY_SCOPE_AGENT);
            if ((uint32_t)(w >> 32) == tagw) break;
            __builtin_amdgcn_s_sleep(1);
          }
        }
      }
      rv = __uint_as_float((uint32_t)w);
    }
  }

  // Tail: outs[TT-1] from final rv (tag TT), block 0 only.
  if (s == 0) {
    float v = rv * who_f;
    #pragma unroll
    for (int off = 32; off > 0; off >>= 1) v += __shfl_down(v, off);
    if (lane == 0) obuf[wv] = v;
    __syncthreads();
    if (tid == 0) {
      float p = ((obuf[0] + obuf[1]) + (obuf[2] + obuf[3])) +
                ((obuf[4] + obuf[5]) + (obuf[6] + obuf[7]));
      outs[b * TT + (TT - 1)] = p + bho;
    }
  }
}

extern "C" void kernel_launch(void* const* d_in, const int* in_sizes, int n_in,
                              void* d_out, int out_size, void* d_ws, size_t ws_size,
                              hipStream_t stream) {
  const float* i_stim = (const float*)d_in[0];
  const float* i_cc   = (const float*)d_in[1];
  const float* hidden = (const float*)d_in[2];
  const float* w_ih   = (const float*)d_in[3];
  // d_in[4] = b_ih — never used by the reference
  const float* w_hh   = (const float*)d_in[5];
  const float* b_hh   = (const float*)d_in[6];
  const float* w_ho   = (const float*)d_in[7];
  const float* b_ho   = (const float*)d_in[8];

  float* outs   = (float*)d_out;                     // [B,T,O]
  float* hids   = (float*)d_out + (size_t)BB * TT;   // [B,T,H]
  uint64_t* pub = (uint64_t*)d_ws;                   // fast (512K) + safe (512K)

  // Kill stale tags from previous graph replays (tags strictly increase
  // within a run, so zeroed words can never falsely match).
  hipMemsetAsync(pub, 0, 2 * PUB_BYTES, stream);

  void* args[] = {(void*)&i_stim, (void*)&i_cc, (void*)&hidden, (void*)&w_ih,
                  (void*)&w_hh, (void*)&b_hh, (void*)&w_ho, (void*)&b_ho,
                  (void*)&outs, (void*)&hids, (void*)&pub};
  hipLaunchCooperativeKernel((const void*)zrnn_main, dim3(NBLK), dim3(512),
                             args, 0, stream);
}

// Round 7
// 4587.211 us; speedup vs baseline: 2.6378x; 2.6378x over previous
//
#include <hip/hip_runtime.h>
#include <stdint.h>
#include <math.h>

#define HH   512
#define BB   64
#define TT   2000
#define NEXC 409          // int(0.8 * 512)
#define SLICE  128        // hidden units owned per block
#define NBLK   (BB * 4)   // 256 blocks = 1 per CU

// Python-float constants, rounded to f32 exactly as the reference does.
constexpr float ALPHA_F     = 0.1f;
constexpr float IN_SCALE_F  = (float)4.4721359549995794e-03;
constexpr float REC_SCALE_F = (float)4.4721359549995794e-02;
constexpr float SQRT2_F     = 1.41421356237309515f;
constexpr float U_LO        = -0x1.fffffep-1f;

struct U2 { uint32_t a, b; };

__host__ __device__ constexpr uint32_t rotl32(uint32_t x, int d) {
  return (x << d) | (x >> (32 - d));
}

// JAX Threefry-2x32, 20 rounds.
__host__ __device__ constexpr U2 tf2x32(uint32_t k0, uint32_t k1,
                                        uint32_t x0, uint32_t x1) {
  uint32_t ks[3] = {k0, k1, k0 ^ k1 ^ 0x1BD11BDAu};
  const int R[2][4] = {{13, 15, 26, 6}, {17, 29, 16, 24}};
  x0 += ks[0]; x1 += ks[1];
  for (int g = 0; g < 5; ++g) {
    const int* r = R[g & 1];
    for (int i = 0; i < 4; ++i) { x0 += x1; x1 = rotl32(x1, r[i]); x1 ^= x0; }
    x0 += ks[(g + 1) % 3];
    x1 += ks[(g + 2) % 3] + (uint32_t)(g + 1);
  }
  return U2{x0, x1};
}

constexpr U2 KIN_  = tf2x32(0u, 42u, 0u, 0u);
constexpr U2 KREC_ = tf2x32(0u, 42u, 0u, 1u);
constexpr uint32_t KIN0 = KIN_.a,  KIN1 = KIN_.b;
constexpr uint32_t KRC0 = KREC_.a, KRC1 = KREC_.b;

__device__ __forceinline__ float jax_normal(uint32_t k0, uint32_t k1, uint32_t idx) {
  U2 o = tf2x32(k0, k1, 0u, idx);
  uint32_t bits = o.a ^ o.b;
  float f = __uint_as_float((bits >> 9) | 0x3f800000u) - 1.0f;  // [0,1)
  float u = fmaxf(U_LO, f * 2.0f + U_LO);
  float w = -log1pf(-u * u);
  float p;
  if (w < 5.0f) {
    w = w - 2.5f;
    p =             2.81022636e-08f;
    p = fmaf(p, w,  3.43273939e-07f);
    p = fmaf(p, w, -3.5233877e-06f);
    p = fmaf(p, w, -4.39150654e-06f);
    p = fmaf(p, w,  0.00021858087f);
    p = fmaf(p, w, -0.00125372503f);
    p = fmaf(p, w, -0.00417768164f);
    p = fmaf(p, w,  0.246640727f);
    p = fmaf(p, w,  1.50140941f);
  } else {
    w = sqrtf(w) - 3.0f;
    p =            -0.000200214257f;
    p = fmaf(p, w,  0.000100950558f);
    p = fmaf(p, w,  0.00134934322f);
    p = fmaf(p, w, -0.00367342844f);
    p = fmaf(p, w,  0.00573950773f);
    p = fmaf(p, w, -0.0076224613f);
    p = fmaf(p, w,  0.00943887047f);
    p = fmaf(p, w,  1.00167406f);
    p = fmaf(p, w,  2.83297682f);
  }
  return SQRT2_F * (p * u);
}

// Workspace: pub[2][BB][HH] uint64, word = (tag << 32) | f32bits(relu(h)).
// tag t+1 = value after step t; slot = (t+1) & 1.  MALL (agent scope) only.
#define PUB_BYTES (2 * BB * HH * 8)   // 512 KB

// Raw workgroup barrier that drains ONLY LDS counters (no vmcnt drain):
// the publish store stays in flight; nobody in this block ever waits on it.
__device__ __forceinline__ void barrier_lds() {
  asm volatile("s_waitcnt lgkmcnt(0)" ::: "memory");
  __builtin_amdgcn_s_barrier();
  asm volatile("" ::: "memory");
}

__device__ __forceinline__ uint64_t pub_ld(const uint64_t* a) {
  return __hip_atomic_load(a, __ATOMIC_RELAXED, __HIP_MEMORY_SCOPE_AGENT);
}

__global__ __launch_bounds__(512, 2)
void zrnn_main(const float* __restrict__ i_stim, const float* __restrict__ i_cc,
               const float* __restrict__ hidden0,
               const float* __restrict__ w_ih, const float* __restrict__ w_hh,
               const float* __restrict__ b_hh,
               const float* __restrict__ w_ho, const float* __restrict__ b_ho,
               float* __restrict__ outs, float* __restrict__ hids,
               uint64_t* __restrict__ pub) {
  // blockIdx -> (batch b, slice s); bid%8 == b&7 (XCD hint only, not relied on).
  const int bid  = blockIdx.x;
  const int low3 = bid & 7;
  const int q    = bid >> 3;
  const int s    = q & 3;
  const int b    = ((q >> 2) << 3) + low3;
  const int tid  = threadIdx.x;
  const int lane = tid & 63;
  const int wv   = tid >> 6;
  const int dwv  = (wv - 2 * s) & 7;  // 0,1=owner waves; 2,3=n_rec; 4=n_in; 5=duty
  const int ownLo = s * SLICE;

  __shared__ float stim_s[TT];
  __shared__ float cc_s[TT];
  __shared__ float red[2][8][SLICE];  // step-parity double-buffered partials
  __shared__ float nbuf[8][SLICE];    // n_rec, slot = step & 7 (written 5 ahead)
  __shared__ float nin_s[8][2];       // n_in, same slotting
  __shared__ float obuf[2][8];        // block-0 output partials, parity = tag & 1

  // Preload this batch's input streams (16 KB LDS), coalesced.
  for (int idx = tid; idx < TT; idx += 512) {
    stim_s[idx] = i_stim[b * TT + idx];
    cc_s[idx]   = i_cc[b * TT + idx];
  }

  // Weight slice in REGISTERS: thread (wv,lane) holds wt[i][j] for
  // i in [64*wv, 64*wv+64), j in {jA, jB}.  wt[i][j] = |w_hh[j][i]|*(i!=j)*ei[i].
  const int jA = ownLo + lane;
  const int jB = jA + 64;
  const int i0 = wv * 64;
  float wA[64], wB[64];
  #pragma unroll
  for (int k4 = 0; k4 < 16; ++k4) {
    float4 a4 = *reinterpret_cast<const float4*>(&w_hh[jA * HH + i0 + k4 * 4]);
    float4 b4 = *reinterpret_cast<const float4*>(&w_hh[jB * HH + i0 + k4 * 4]);
    const float av[4] = {a4.x, a4.y, a4.z, a4.w};
    const float bv[4] = {b4.x, b4.y, b4.z, b4.w};
    #pragma unroll
    for (int c = 0; c < 4; ++c) {
      const int i = i0 + k4 * 4 + c;
      float va = (i == jA) ? 0.0f : fabsf(av[c]);
      float vb = (i == jB) ? 0.0f : fabsf(bv[c]);
      wA[k4 * 4 + c] = (i < NEXC) ? va : -va;
      wB[k4 * 4 + c] = (i < NEXC) ? vb : -vb;
    }
  }

  // Owners: waves 2s,2s+1 -> thread tid owns hidden unit j == tid.
  float h = 0.0f, wih0 = 0.0f, wih1 = 0.0f, bhh = 0.0f;
  if (dwv < 2) {
    h    = hidden0[b * HH + tid];
    wih0 = w_ih[tid * 2 + 0];
    wih1 = w_ih[tid * 2 + 1];
    bhh  = b_hh[tid];
  }
  const float who_f = w_ho[tid];
  const float bho   = b_ho[0];

  // rv: thread tid holds relu(h[i = tid]); primed from hidden0.
  float rv = fmaxf(hidden0[b * HH + tid], 0.0f);

  // Noise prefill for steps 0..4 (5 slots): 640 n_rec + 10 n_in.
  for (int e = tid; e < 5 * SLICE; e += 512) {
    const int tp = e >> 7;        // 0..4
    const int jn = e & 127;
    nbuf[tp][jn] = jax_normal(KRC0, KRC1,
        (uint32_t)tp * (uint32_t)(BB * HH) + (uint32_t)(b * HH + ownLo + jn));
  }
  if (tid < 10) {
    nin_s[tid >> 1][tid & 1] = jax_normal(KIN0, KIN1,
        (uint32_t)((tid >> 1) * (BB * 2) + b * 2 + (tid & 1)));
  }

  uint64_t* pub_b0 = pub + (size_t)b * HH;
  uint64_t* pub_b1 = pub + (size_t)(BB + b) * HH;
  float* __restrict__ hid_out = hids + (size_t)b * TT * HH;

  __syncthreads();

  for (int t = 0; t < TT; ++t) {
    const int par = t & 1;

    // Block 0: per-wave output partials from registers (rv = tag t), and the
    // duty lane finalizes out[t-2] from the opposite-parity buffer.
    if (s == 0) {
      float v = rv * who_f;
      #pragma unroll
      for (int off = 32; off > 0; off >>= 1) v += __shfl_down(v, off);
      if (lane == 0) obuf[par][wv] = v;
      if (dwv == 5 && lane == 0 && t >= 2) {
        const float* ob = obuf[par ^ 1];
        float p = ((ob[0] + ob[1]) + (ob[2] + ob[3])) +
                  ((ob[4] + ob[5]) + (ob[6] + ob[7]));
        outs[b * TT + (t - 2)] = p + bho;
      }
    }

    // Matvec partials — readlane-broadcast rv, register weights.
    float accA = 0.0f, accB = 0.0f;
    #pragma unroll
    for (int k = 0; k < 64; ++k) {
      float rk = __uint_as_float(__builtin_amdgcn_readlane(__float_as_uint(rv), k));
      accA = fmaf(rk, wA[k], accA);
      accB = fmaf(rk, wB[k], accB);
    }
    red[par][wv][lane]      = accA;
    red[par][wv][64 + lane] = accB;

    barrier_lds();  // A_t — the only barrier per step; LDS counters only.

    uint64_t* pub_t = ((t + 1) & 1) ? pub_b1 : pub_b0;

    if (dwv < 2) {
      // Owners: combine 8 chunks (increasing-i), update h, publish, reg refresh.
      const int jloc = tid - ownLo;
      float acc = red[par][0][jloc];
      #pragma unroll
      for (int w = 1; w < 8; ++w) acc += red[par][w][jloc];
      float nr  = nbuf[t & 7][jloc];
      float ni0 = nin_s[t & 7][0];
      float ni1 = nin_s[t & 7][1];
      float hid_hid = acc + bhh + REC_SCALE_F * nr;
      float cur0 = fmaxf(stim_s[t] + IN_SCALE_F * ni0, 0.0f);
      float cur1 = fmaxf(cc_s[t]   + IN_SCALE_F * ni1, 0.0f);
      float hid_in = cur0 * wih0 + cur1 * wih1;
      h = h + (-h + hid_in + hid_hid) * ALPHA_F;
      float r = fmaxf(h, 0.0f);
      uint64_t wd = ((uint64_t)(uint32_t)(t + 1) << 32) |
                    (uint64_t)__float_as_uint(r);
      __hip_atomic_store(&pub_t[tid], wd, __ATOMIC_RELAXED,
                         __HIP_MEMORY_SCOPE_AGENT);   // fire-and-forget
      rv = r;
      __builtin_nontemporal_store(h, hid_out + (size_t)t * HH + tid);
    } else {
      // Designated waves generate noise for step t+5 (slot (t+5)&7 != t&7),
      // then join the poll. Owner path never touches threefry.
      if (t + 5 < TT) {
        if (dwv == 2) {
          nbuf[(t + 5) & 7][lane] = jax_normal(KRC0, KRC1,
              (uint32_t)(t + 5) * (uint32_t)(BB * HH) +
              (uint32_t)(b * HH + ownLo + lane));
        } else if (dwv == 3) {
          nbuf[(t + 5) & 7][64 + lane] = jax_normal(KRC0, KRC1,
              (uint32_t)(t + 5) * (uint32_t)(BB * HH) +
              (uint32_t)(b * HH + ownLo + 64 + lane));
        } else if (dwv == 4 && lane < 2) {
          nin_s[(t + 5) & 7][lane] = jax_normal(KIN0, KIN1,
              (uint32_t)((t + 5) * (BB * 2) + b * 2 + lane));
        }
      }
      // Depth-4 pipelined tagged-word poll: ~RT/4 discovery granularity.
      const uint32_t tagw = (uint32_t)(t + 1);
      const uint64_t* a = &pub_t[tid];
      uint64_t w0 = pub_ld(a);
      uint64_t w1 = pub_ld(a);
      uint64_t w2 = pub_ld(a);
      uint64_t w3 = pub_ld(a);
      while ((uint32_t)(w0 >> 32) != tagw) {
        w0 = w1; w1 = w2; w2 = w3;
        w3 = pub_ld(a);
      }
      rv = __uint_as_float((uint32_t)w0);
    }
  }

  // Tail: outs[TT-2] (from obuf parity (TT-1)&1) and outs[TT-1] (rv = tag TT).
  if (s == 0) {
    if (dwv == 5 && lane == 0) {
      const float* ob = obuf[(TT - 1) & 1];
      float p = ((ob[0] + ob[1]) + (ob[2] + ob[3])) +
                ((ob[4] + ob[5]) + (ob[6] + ob[7]));
      outs[b * TT + (TT - 2)] = p + bho;
    }
    float v = rv * who_f;
    #pragma unroll
    for (int off = 32; off > 0; off >>= 1) v += __shfl_down(v, off);
    if (lane == 0) obuf[TT & 1][wv] = v;
    __syncthreads();
    if (dwv == 5 && lane == 0) {
      const float* ob = obuf[TT & 1];
      float p = ((ob[0] + ob[1]) + (ob[2] + ob[3])) +
                ((ob[4] + ob[5]) + (ob[6] + ob[7]));
      outs[b * TT + (TT - 1)] = p + bho;
    }
  }
}

extern "C" void kernel_launch(void* const* d_in, const int* in_sizes, int n_in,
                              void* d_out, int out_size, void* d_ws, size_t ws_size,
                              hipStream_t stream) {
  const float* i_stim = (const float*)d_in[0];
  const float* i_cc   = (const float*)d_in[1];
  const float* hidden = (const float*)d_in[2];
  const float* w_ih   = (const float*)d_in[3];
  // d_in[4] = b_ih — never used by the reference
  const float* w_hh   = (const float*)d_in[5];
  const float* b_hh   = (const float*)d_in[6];
  const float* w_ho   = (const float*)d_in[7];
  const float* b_ho   = (const float*)d_in[8];

  float* outs   = (float*)d_out;                     // [B,T,O]
  float* hids   = (float*)d_out + (size_t)BB * TT;   // [B,T,H]
  uint64_t* pub = (uint64_t*)d_ws;

  // Kill stale tags from previous graph replays (tags strictly increase
  // within a run, so zeroed words can never falsely match).
  hipMemsetAsync(pub, 0, PUB_BYTES, stream);

  void* args[] = {(void*)&i_stim, (void*)&i_cc, (void*)&hidden, (void*)&w_ih,
                  (void*)&w_hh, (void*)&b_hh, (void*)&w_ho, (void*)&b_ho,
                  (void*)&outs, (void*)&hids, (void*)&pub};
  hipLaunchCooperativeKernel((const void*)zrnn_main, dim3(NBLK), dim3(512),
                             args, 0, stream);
}

// Round 9
// 3982.270 us; speedup vs baseline: 3.0385x; 1.1519x over previous
//
#include <hip/hip_runtime.h>
#include <stdint.h>
#include <math.h>

#define HH   512
#define BB   64
#define TT   2000
#define NEXC 409          // int(0.8 * 512)
#define SLICE  128        // hidden units owned per block
#define NBLK   (BB * 4)   // 256 blocks = 1 per CU

// Python-float constants, rounded to f32 exactly as the reference does.
constexpr float ALPHA_F     = 0.1f;
constexpr float IN_SCALE_F  = (float)4.4721359549995794e-03;
constexpr float REC_SCALE_F = (float)4.4721359549995794e-02;
constexpr float SQRT2_F     = 1.41421356237309515f;
constexpr float U_LO        = -0x1.fffffep-1f;

struct U2 { uint32_t a, b; };

__host__ __device__ constexpr uint32_t rotl32(uint32_t x, int d) {
  return (x << d) | (x >> (32 - d));
}

// JAX Threefry-2x32, 20 rounds.
__host__ __device__ constexpr U2 tf2x32(uint32_t k0, uint32_t k1,
                                        uint32_t x0, uint32_t x1) {
  uint32_t ks[3] = {k0, k1, k0 ^ k1 ^ 0x1BD11BDAu};
  const int R[2][4] = {{13, 15, 26, 6}, {17, 29, 16, 24}};
  x0 += ks[0]; x1 += ks[1];
  for (int g = 0; g < 5; ++g) {
    const int* r = R[g & 1];
    for (int i = 0; i < 4; ++i) { x0 += x1; x1 = rotl32(x1, r[i]); x1 ^= x0; }
    x0 += ks[(g + 1) % 3];
    x1 += ks[(g + 2) % 3] + (uint32_t)(g + 1);
  }
  return U2{x0, x1};
}

constexpr U2 KIN_  = tf2x32(0u, 42u, 0u, 0u);
constexpr U2 KREC_ = tf2x32(0u, 42u, 0u, 1u);
constexpr uint32_t KIN0 = KIN_.a,  KIN1 = KIN_.b;
constexpr uint32_t KRC0 = KREC_.a, KRC1 = KREC_.b;

__device__ __forceinline__ float jax_normal(uint32_t k0, uint32_t k1, uint32_t idx) {
  U2 o = tf2x32(k0, k1, 0u, idx);
  uint32_t bits = o.a ^ o.b;
  float f = __uint_as_float((bits >> 9) | 0x3f800000u) - 1.0f;  // [0,1)
  float u = fmaxf(U_LO, f * 2.0f + U_LO);
  float w = -log1pf(-u * u);
  float p;
  if (w < 5.0f) {
    w = w - 2.5f;
    p =             2.81022636e-08f;
    p = fmaf(p, w,  3.43273939e-07f);
    p = fmaf(p, w, -3.5233877e-06f);
    p = fmaf(p, w, -4.39150654e-06f);
    p = fmaf(p, w,  0.00021858087f);
    p = fmaf(p, w, -0.00125372503f);
    p = fmaf(p, w, -0.00417768164f);
    p = fmaf(p, w,  0.246640727f);
    p = fmaf(p, w,  1.50140941f);
  } else {
    w = sqrtf(w) - 3.0f;
    p =            -0.000200214257f;
    p = fmaf(p, w,  0.000100950558f);
    p = fmaf(p, w,  0.00134934322f);
    p = fmaf(p, w, -0.00367342844f);
    p = fmaf(p, w,  0.00573950773f);
    p = fmaf(p, w, -0.0076224613f);
    p = fmaf(p, w,  0.00943887047f);
    p = fmaf(p, w,  1.00167406f);
    p = fmaf(p, w,  2.83297682f);
  }
  return SQRT2_F * (p * u);
}

// Workspace: pub[2][BB][HH] uint64 words, each = (step_tag << 32) | f32bits(relu(h)).
// Tag travels WITH the data in one atomic 8B word -> single MALL leg per exchange.
#define PUB_WORDS (2 * BB * HH)
#define PUB_BYTES (PUB_WORDS * 8)   // 512 KB

__device__ __forceinline__ uint64_t pub_ld(const uint64_t* a) {
  return __hip_atomic_load(a, __ATOMIC_RELAXED, __HIP_MEMORY_SCOPE_AGENT);
}

__global__ __launch_bounds__(512, 2)
void zrnn_main(const float* __restrict__ i_stim, const float* __restrict__ i_cc,
               const float* __restrict__ hidden0,
               const float* __restrict__ w_ih, const float* __restrict__ w_hh,
               const float* __restrict__ b_hh,
               const float* __restrict__ w_ho, const float* __restrict__ b_ho,
               float* __restrict__ outs, float* __restrict__ hids,
               uint64_t* __restrict__ pub) {
  // blockIdx -> (batch b, slice s); same-batch siblings share blockIdx%8 so they
  // land on one XCD under round-robin dispatch (perf-only assumption).
  const int bid  = blockIdx.x;
  const int low3 = bid & 7;
  const int q    = bid >> 3;
  const int s    = q & 3;
  const int b    = ((q >> 2) << 3) + low3;
  const int tid  = threadIdx.x;
  const int lane = tid & 63;
  const int wv   = tid >> 6;          // wave id = i-chunk id

  __shared__ float stim_s[TT];
  __shared__ float cc_s[TT];
  __shared__ float red[8][SLICE];     // per-wave matvec partials
  __shared__ float rloc[SLICE];       // own-slice relu(h) fast path (skip MALL)
  __shared__ float nbuf[4][SLICE];    // n_rec, 4 steps ahead
  __shared__ float nin_s[4][2];       // n_in,  4 steps ahead
  __shared__ float obuf[8];           // block-0 output partials

  // Preload this batch's input streams (16 KB LDS), coalesced.
  for (int idx = tid; idx < TT; idx += 512) {
    stim_s[idx] = i_stim[b * TT + idx];
    cc_s[idx]   = i_cc[b * TT + idx];
  }

  // Weight slice in REGISTERS: thread (wv,lane) holds wt[i][j] for
  // i in [64*wv, 64*wv+64), j in {jA, jB}.  wt[i][j] = |w_hh[j][i]|*(i!=j)*ei[i].
  const int jA = s * SLICE + lane;
  const int jB = jA + 64;
  const int i0 = wv * 64;
  float wA[64], wB[64];
  #pragma unroll
  for (int k4 = 0; k4 < 16; ++k4) {
    float4 a4 = *reinterpret_cast<const float4*>(&w_hh[jA * HH + i0 + k4 * 4]);
    float4 b4 = *reinterpret_cast<const float4*>(&w_hh[jB * HH + i0 + k4 * 4]);
    const float av[4] = {a4.x, a4.y, a4.z, a4.w};
    const float bv[4] = {b4.x, b4.y, b4.z, b4.w};
    #pragma unroll
    for (int c = 0; c < 4; ++c) {
      const int i = i0 + k4 * 4 + c;
      float va = (i == jA) ? 0.0f : fabsf(av[c]);
      float vb = (i == jB) ? 0.0f : fabsf(bv[c]);
      wA[k4 * 4 + c] = (i < NEXC) ? va : -va;
      wB[k4 * 4 + c] = (i < NEXC) ? vb : -vb;
    }
  }

  // Hidden-state owners: threads 0..127 own j = s*128 + tid.
  float h = 0.0f, wih0 = 0.0f, wih1 = 0.0f, bhh = 0.0f;
  const int jown = s * SLICE + tid;
  if (tid < SLICE) {
    h    = hidden0[b * HH + jown];
    wih0 = w_ih[jown * 2 + 0];
    wih1 = w_ih[jown * 2 + 1];
    bhh  = b_hh[jown];
  }
  // Block s==0 computes the output scalar from its full rv vector.
  float who_f = 0.0f, bho = 0.0f;
  if (s == 0) { who_f = w_ho[tid]; bho = b_ho[0]; }

  // rv: lane mapping i = tid; primed from hidden0.
  float rv = fmaxf(hidden0[b * HH + tid], 0.0f);

  // Noise prefill for steps 0..3.
  {
    const int tp = tid >> 7;
    const int jn = tid & 127;
    nbuf[tp][jn] = jax_normal(KRC0, KRC1,
        (uint32_t)tp * (uint32_t)(BB * HH) + (uint32_t)(b * HH + s * SLICE + jn));
    if (tid < 8) {
      const int tp2  = tid >> 1;
      const int slot = tid & 1;
      nin_s[tp2][slot] = jax_normal(KIN0, KIN1,
          (uint32_t)(tp2 * (BB * 2) + b * 2 + slot));
    }
  }

  const int  ownLo     = s * SLICE;
  const bool isOwnLane = (tid >= ownLo) && (tid < ownLo + SLICE);
  uint64_t* pub_b0 = pub + (size_t)b * HH;
  uint64_t* pub_b1 = pub + (size_t)(BB + b) * HH;
  float* __restrict__ hid_out = hids + (size_t)b * TT * HH;

  __syncthreads();

  for (int t = 0; t < TT; ++t) {
    // Block 0: previous step's output scalar from rv (tag t) — off critical path.
    if (s == 0 && t > 0) {
      float v = rv * who_f;
      #pragma unroll
      for (int off = 32; off > 0; off >>= 1) v += __shfl_down(v, off);
      if (lane == 0) obuf[wv] = v;
    }

    // A: matvec partials — readlane-broadcast rv, register weights.
    float accA = 0.0f, accB = 0.0f;
    #pragma unroll
    for (int k = 0; k < 64; ++k) {
      float rk = __uint_as_float(__builtin_amdgcn_readlane(__float_as_uint(rv), k));
      accA = fmaf(rk, wA[k], accA);
      accB = fmaf(rk, wB[k], accB);
    }
    red[wv][lane]      = accA;
    red[wv][64 + lane] = accB;
    __syncthreads();  // barrier 1: red ready (also orders obuf write -> read)

    uint64_t* pub_t = (t & 1) ? pub_b1 : pub_b0;

    // C: owners combine chunks (increasing-i), update h, publish tagged word.
    if (tid < SLICE) {
      float acc = red[0][tid];
      #pragma unroll
      for (int w = 1; w < 8; ++w) acc += red[w][tid];
      float nr = nbuf[t & 3][tid];
      float hid_hid = acc + bhh + REC_SCALE_F * nr;
      float ni0 = nin_s[t & 3][0];
      float ni1 = nin_s[t & 3][1];
      float cur0 = fmaxf(stim_s[t] + IN_SCALE_F * ni0, 0.0f);
      float cur1 = fmaxf(cc_s[t]   + IN_SCALE_F * ni1, 0.0f);
      float hid_in = cur0 * wih0 + cur1 * wih1;
      h = h + (-h + hid_in + hid_hid) * ALPHA_F;
      float r = fmaxf(h, 0.0f);
      uint64_t wd = ((uint64_t)(uint32_t)(t + 1) << 32) |
                    (uint64_t)__float_as_uint(r);
      __hip_atomic_store(&pub_t[jown], wd, __ATOMIC_RELAXED,
                         __HIP_MEMORY_SCOPE_AGENT);
      rloc[tid] = r;
      __builtin_nontemporal_store(h, hid_out + (size_t)t * HH + jown);
      if (s == 0 && tid == 0 && t > 0) {
        float p = ((obuf[0] + obuf[1]) + (obuf[2] + obuf[3])) +
                  ((obuf[4] + obuf[5]) + (obuf[6] + obuf[7]));
        outs[b * TT + (t - 1)] = p + bho;
      }
    }
    __syncthreads();  // barrier 2: rloc ready; red free for reuse

    // F: overlap the wait with noise precompute for t+1..t+4.
    if ((t & 3) == 3 && t + 1 < TT) {
      const int tp = t + 1 + (tid >> 7);
      if (tp < TT) {
        const int jn = tid & 127;
        nbuf[tp & 3][jn] = jax_normal(KRC0, KRC1,
            (uint32_t)tp * (uint32_t)(BB * HH) + (uint32_t)(b * HH + s * SLICE + jn));
      }
      if (tid < 8) {
        const int tp2  = t + 1 + (tid >> 1);
        const int slot = tid & 1;
        if (tp2 < TT)
          nin_s[tp2 & 3][slot] = jax_normal(KIN0, KIN1,
              (uint32_t)(tp2 * (BB * 2) + b * 2 + slot));
      }
    }

    // H: refresh rv. Own slice via LDS; remote via PACED 2-deep tagged-word
    // poll (sleep every iteration -> ~6-8x less fabric traffic than hot spin;
    // 2 loads stay in flight so discovery adds <= ~RT + sleep quantum).
    if (isOwnLane) {
      rv = rloc[tid - ownLo];
    } else {
      const uint32_t tagw = (uint32_t)(t + 1);
      const uint64_t* a = &pub_t[tid];
      uint64_t w0 = pub_ld(a);
      if ((uint32_t)(w0 >> 32) != tagw) {
        uint64_t w1 = pub_ld(a);
        int it = 0;
        while ((uint32_t)(w0 >> 32) != tagw) {
          ++it;
          if (it > 64) __builtin_amdgcn_s_sleep(8);
          else         __builtin_amdgcn_s_sleep(1);
          w0 = w1;
          w1 = pub_ld(a);
        }
      }
      rv = __uint_as_float((uint32_t)w0);
    }
  }

  // Tail: outs[TT-1] from final rv (tag TT).
  if (s == 0) {
    float v = rv * who_f;
    #pragma unroll
    for (int off = 32; off > 0; off >>= 1) v += __shfl_down(v, off);
    if (lane == 0) obuf[wv] = v;
    __syncthreads();
    if (tid == 0) {
      float p = ((obuf[0] + obuf[1]) + (obuf[2] + obuf[3])) +
                ((obuf[4] + obuf[5]) + (obuf[6] + obuf[7]));
      outs[b * TT + (TT - 1)] = p + bho;
    }
  }
}

extern "C" void kernel_launch(void* const* d_in, const int* in_sizes, int n_in,
                              void* d_out, int out_size, void* d_ws, size_t ws_size,
                              hipStream_t stream) {
  const float* i_stim = (const float*)d_in[0];
  const float* i_cc   = (const float*)d_in[1];
  const float* hidden = (const float*)d_in[2];
  const float* w_ih   = (const float*)d_in[3];
  // d_in[4] = b_ih — never used by the reference
  const float* w_hh   = (const float*)d_in[5];
  const float* b_hh   = (const float*)d_in[6];
  const float* w_ho   = (const float*)d_in[7];
  const float* b_ho   = (const float*)d_in[8];

  float* outs   = (float*)d_out;                     // [B,T,O]
  float* hids   = (float*)d_out + (size_t)BB * TT;   // [B,T,H]
  uint64_t* pub = (uint64_t*)d_ws;

  // Kill stale tags from previous graph replays (tags strictly increase
  // within a run, so zeroed words can never falsely match).
  hipMemsetAsync(pub, 0, PUB_BYTES, stream);

  void* args[] = {(void*)&i_stim, (void*)&i_cc, (void*)&hidden, (void*)&w_ih,
                  (void*)&w_hh, (void*)&b_hh, (void*)&w_ho, (void*)&b_ho,
                  (void*)&outs, (void*)&hids, (void*)&pub};
  hipLaunchCooperativeKernel((const void*)zrnn_main, dim3(NBLK), dim3(512),
                             args, 0, stream);
}